// Round 6
// baseline (498.994 us; speedup 1.0000x reference)
//
#include <hip/hip_runtime.h>
#include <hip/hip_bf16.h>
#include <stdint.h>

#define NN 50000
#define NE 800000
#define CC 96
#define NL 3

// packed-weight geometry: per layer, per tcol: 9 frag-sets (part*3+gate) x 3 ks x 64 lanes x 8 bf16
#define FRAGS_PER_TCOL 1728              // 9*3*64
#define ELEMS_PER_TCOL 13824             // FRAGS*8
#define ELEMS_PER_LAYER 82944            // 6*ELEMS_PER_TCOL
#define SROW 100                         // padded LDS row stride (floats): 96+4 -> 2-way bank alias (free)

typedef __bf16 bf16x8 __attribute__((ext_vector_type(8)));
typedef float f32x4 __attribute__((ext_vector_type(4)));

__device__ __forceinline__ uint16_t f2bf(float f){
  uint32_t u = __builtin_bit_cast(uint32_t, f);
  uint32_t r = (u + 0x7fffu + ((u >> 16) & 1u)) >> 16;
  return (uint16_t)r;
}
__device__ __forceinline__ float bf2f(uint16_t h){
  uint32_t u = ((uint32_t)h) << 16;
  return __builtin_bit_cast(float, u);
}
__device__ __forceinline__ void split_bf(float f, uint16_t& hi, uint16_t& lo){
  hi = f2bf(f);
  lo = f2bf(f - bf2f(hi));
}
// load 8 contiguous f32 (generic addrspace: works for LDS or global) and split
// to hi/lo bf16x8 fragments in-register
__device__ __forceinline__ void split8(const float* p, bf16x8& h8, bf16x8& l8){
  float4 a = *(const float4*)p;
  float4 b = *(const float4*)(p+4);
  float v[8] = {a.x,a.y,a.z,a.w,b.x,b.y,b.z,b.w};
  #pragma unroll
  for(int j=0;j<8;j++){
    uint16_t hi, lo; split_bf(v[j], hi, lo);
    h8[j] = __builtin_bit_cast(__bf16, hi);
    l8[j] = __builtin_bit_cast(__bf16, lo);
  }
}

__global__ void k_zero(int* counts, int* gcur){
  int i = blockIdx.x*256 + threadIdx.x;
  if(i < NN) counts[i] = 0;
  if(i == 0) *gcur = 0;
}

__global__ void k_hist(const int* __restrict__ dstv, int* __restrict__ counts){
  int e = blockIdx.x*256 + threadIdx.x;
  if(e < NE) atomicAdd(&counts[dstv[e]], 1);
}

// Scan-free bucket assignment: CSR bucket ORDER is arbitrary — wave-prefix-scan
// counts, one atomicAdd on a global cursor per wave grabs the bucket range.
__global__ void k_assign(const int* __restrict__ counts, int* __restrict__ offsets,
                         int* __restrict__ cursor, int* __restrict__ gcur){
  int i = blockIdx.x*256 + threadIdx.x;
  int lane = threadIdx.x & 63;
  int v = (i < NN) ? counts[i] : 0;
  int sum = v;
  #pragma unroll
  for(int d=1; d<64; d<<=1){
    int t = __shfl_up(sum, d, 64);
    if(lane >= d) sum += t;
  }
  int total = __shfl(sum, 63, 64);
  int base = 0;
  if(lane == 63) base = atomicAdd(gcur, total);
  base = __shfl(base, 63, 64);
  int off = base + sum - v;
  if(i < NN){ offsets[i] = off; cursor[i] = off; }
}

__global__ void k_fill(const int* __restrict__ srcv, const int* __restrict__ dstv,
                       int* __restrict__ cursor, int* __restrict__ ssrc){
  int e = blockIdx.x*256 + threadIdx.x;
  if(e < NE){
    int d = dstv[e];
    int pos = atomicAdd(&cursor[d], 1);
    ssrc[pos] = srcv[e];
  }
}

// Pack weights in MFMA-fragment-linear order.
// gw[l][tcol][pg][ks][lane][8], pg = part*3+gate; part 0=Wc_hi, 1=Wc_lo, 2=Whh(hi only).
// B-frag mapping (16x16x32): n = lane&15, k = (lane>>4)*8 + j.
__device__ __forceinline__ size_t frag_elem(int tcol, int part, int g, int ks, int lane, int j){
  return ((size_t)((tcol*9 + part*3 + g)*3 + ks)*64 + lane)*8 + j;
}
__global__ void k_pack_w(const float* __restrict__ weight, const float* __restrict__ w_ih,
                         const float* __restrict__ w_hh, uint16_t* __restrict__ gw){
  int idx = blockIdx.x*256 + threadIdx.x;
  const int TOT1 = NL*288*CC;     // Wc threads: (l, col, k)
  const int TOT2 = 288*CC;        // Whh threads: (col, k) -> replicate to all 3 layers
  if(idx < TOT1){
    int k = idx % CC;
    int col = (idx / CC) % 288;
    int l = idx / (CC*288);
    const float4* wr = (const float4*)(weight + (size_t)(l*CC + k)*CC);
    const float4* ir = (const float4*)(w_ih + (size_t)col*CC);
    float acc = 0.f;
    #pragma unroll 4
    for(int k2=0;k2<CC/4;k2++){
      float4 a = wr[k2], b = ir[k2];
      acc += a.x*b.x + a.y*b.y + a.z*b.z + a.w*b.w;
    }
    uint16_t h, lo; split_bf(acc, h, lo);
    int g = col / 96, cg = col % 96;
    int tcol = cg >> 4, n = cg & 15;
    int ks = k >> 5, r = (k & 31) >> 3, j = k & 7;
    int lane = r*16 + n;
    size_t lb = (size_t)l*ELEMS_PER_LAYER;
    gw[lb + frag_elem(tcol, 0, g, ks, lane, j)] = h;
    gw[lb + frag_elem(tcol, 1, g, ks, lane, j)] = lo;
  } else {
    int idx2 = idx - TOT1;
    if(idx2 < TOT2){
      int k = idx2 % CC;
      int col = idx2 / CC;
      uint16_t h = f2bf(w_hh[(size_t)col*CC + k]);
      int g = col / 96, cg = col % 96;
      int tcol = cg >> 4, n = cg & 15;
      int ks = k >> 5, r = (k & 31) >> 3, j = k & 7;
      int lane = r*16 + n;
      size_t fe = frag_elem(tcol, 2, g, ks, lane, j);
      #pragma unroll
      for(int l=0;l<NL;l++) gw[(size_t)l*ELEMS_PER_LAYER + fe] = h;
    }
  }
}

#define MFMA(A,B,C) __builtin_amdgcn_mfma_f32_16x16x32_bf16(A,B,C,0,0,0)

// Fused aggregate + dual-GEMM + GRU. Block = 64 nodes (4 mtiles).
// Phase 1: CSR-gather the block's 64 s-rows into padded LDS (overlapped with
// staging tcol0 weights). Phase 2: per-tcol LDS-staged weights + MFMA + epilogue.
// LDS: 25.6KB (s tile) + 27KB (weights) = 53.2KB -> 3 blocks/CU.
__global__ __launch_bounds__(256, 3) void k_gru_fused(
    const float* __restrict__ xf, const int* __restrict__ offsets,
    const int* __restrict__ counts, const int* __restrict__ ssrc,
    const uint16_t* __restrict__ gw_l,
    const float* __restrict__ b_ih, const float* __restrict__ b_hh,
    float* __restrict__ out_f)
{
  __shared__ __align__(16) float s_lds[64*SROW];          // 25600 B
  __shared__ __align__(16) uint16_t lw[ELEMS_PER_TCOL];   // 27648 B

  const int tid = threadIdx.x;

  // stage tcol0 weights (no dependence on gather)
  {
    const uint4* src = (const uint4*)gw_l;
    uint4* dst = (uint4*)lw;
    #pragma unroll
    for(int i=0;i<7;i++){
      int chunk = i*256 + tid;
      if(chunk < FRAGS_PER_TCOL) dst[chunk] = src[chunk];
    }
  }

  // gather s for this block's 64 nodes: 1536 tasks = 64 nodes x 24 c4-groups
  {
    int nbase = blockIdx.x*64;
    const float4* xf4 = (const float4*)xf;
    #pragma unroll 1
    for(int i=0;i<6;i++){
      int t = i*256 + tid;
      int nl = t / 24, c4 = t - nl*24;
      int node = nbase + nl;
      if(node < NN){
        int o0 = offsets[node];
        int o1 = o0 + counts[node];
        float ax=0.f, ay=0.f, az=0.f, aw=0.f;
        int j = o0;
        for(; j+8 <= o1; j+=8){
          int s0 = ssrc[j],   s1 = ssrc[j+1], s2 = ssrc[j+2], s3 = ssrc[j+3];
          int s4 = ssrc[j+4], s5 = ssrc[j+5], s6 = ssrc[j+6], s7 = ssrc[j+7];
          float4 v0 = xf4[(size_t)s0*(CC/4) + c4];
          float4 v1 = xf4[(size_t)s1*(CC/4) + c4];
          float4 v2 = xf4[(size_t)s2*(CC/4) + c4];
          float4 v3 = xf4[(size_t)s3*(CC/4) + c4];
          float4 v4 = xf4[(size_t)s4*(CC/4) + c4];
          float4 v5 = xf4[(size_t)s5*(CC/4) + c4];
          float4 v6 = xf4[(size_t)s6*(CC/4) + c4];
          float4 v7 = xf4[(size_t)s7*(CC/4) + c4];
          ax += (v0.x+v1.x)+(v2.x+v3.x)+((v4.x+v5.x)+(v6.x+v7.x));
          ay += (v0.y+v1.y)+(v2.y+v3.y)+((v4.y+v5.y)+(v6.y+v7.y));
          az += (v0.z+v1.z)+(v2.z+v3.z)+((v4.z+v5.z)+(v6.z+v7.z));
          aw += (v0.w+v1.w)+(v2.w+v3.w)+((v4.w+v5.w)+(v6.w+v7.w));
        }
        for(; j < o1; j++){
          float4 v = xf4[(size_t)ssrc[j]*(CC/4) + c4];
          ax += v.x; ay += v.y; az += v.z; aw += v.w;
        }
        float4 o; o.x=ax; o.y=ay; o.z=az; o.w=aw;
        *(float4*)(s_lds + nl*SROW + c4*4) = o;
      }
    }
  }
  __syncthreads();

  int wave = tid >> 6;
  int lane = tid & 63;
  int mtile = blockIdx.x*4 + wave;
  bool valid = (mtile < NN/16);
  int mt = valid ? mtile : (NN/16 - 1);   // clamp global addrs; no early return
  int nidx = lane & 15;
  int quad = lane >> 4;

  // A fragments: s from LDS (2-way bank alias only), x from global; split hi/lo
  bf16x8 ash[3], asl[3], axh[3], axl[3];
  {
    const float* srow = s_lds + (size_t)(wave*16 + nidx)*SROW;
    size_t xrow = (size_t)(mt*16 + nidx)*CC;
    #pragma unroll
    for(int ks=0; ks<3; ks++){
      int ko = ks*32 + quad*8;
      split8(srow + ko, ash[ks], asl[ks]);
      split8(xf + xrow + ko, axh[ks], axl[ks]);
    }
  }

  #pragma unroll 1
  for(int tcol=0; tcol<6; tcol++){
    if(tcol > 0){
      __syncthreads();                   // all waves done reading prior tcol
      const uint4* src = (const uint4*)(gw_l + (size_t)tcol*ELEMS_PER_TCOL);
      uint4* dst = (uint4*)lw;
      #pragma unroll
      for(int i=0;i<7;i++){
        int chunk = i*256 + tid;
        if(chunk < FRAGS_PER_TCOL) dst[chunk] = src[chunk];
      }
      __syncthreads();
    }

    f32x4 air = {0.f,0.f,0.f,0.f}, aiz = {0.f,0.f,0.f,0.f}, ain = {0.f,0.f,0.f,0.f};
    f32x4 ahr = {0.f,0.f,0.f,0.f}, ahz = {0.f,0.f,0.f,0.f}, ahn = {0.f,0.f,0.f,0.f};

    #pragma unroll
    for(int ks=0; ks<3; ks++){
      const uint16_t* base = lw + ((size_t)ks*64 + lane)*8;
      #define BFRAG(part,g) (*reinterpret_cast<const bf16x8*>(base + (size_t)((part)*3+(g))*3*64*8))
      bf16x8 b;
      b = BFRAG(0,0); air = MFMA(ash[ks], b, air); air = MFMA(asl[ks], b, air);
      b = BFRAG(1,0); air = MFMA(ash[ks], b, air);
      b = BFRAG(0,1); aiz = MFMA(ash[ks], b, aiz); aiz = MFMA(asl[ks], b, aiz);
      b = BFRAG(1,1); aiz = MFMA(ash[ks], b, aiz);
      b = BFRAG(0,2); ain = MFMA(ash[ks], b, ain); ain = MFMA(asl[ks], b, ain);
      b = BFRAG(1,2); ain = MFMA(ash[ks], b, ain);
      b = BFRAG(2,0); ahr = MFMA(axh[ks], b, ahr); ahr = MFMA(axl[ks], b, ahr);
      b = BFRAG(2,1); ahz = MFMA(axh[ks], b, ahz); ahz = MFMA(axl[ks], b, ahz);
      b = BFRAG(2,2); ahn = MFMA(axh[ks], b, ahn); ahn = MFMA(axl[ks], b, ahn);
      #undef BFRAG
    }

    int c = tcol*16 + nidx;
    float bir_ = b_ih[c], biz_ = b_ih[CC+c], bin_ = b_ih[2*CC+c];
    float bhr_ = b_hh[c], bhz_ = b_hh[CC+c], bhn_ = b_hh[2*CC+c];

    #pragma unroll
    for(int r=0;r<4;r++){
      int node = mt*16 + quad*4 + r;     // C/D: row = quad*4 + reg, col = lane&15
      float ir  = air[r] + bir_;
      float iz  = aiz[r] + biz_;
      float in_ = ain[r] + bin_;
      float hr  = ahr[r] + bhr_;
      float hz  = ahz[r] + bhz_;
      float hn  = ahn[r] + bhn_;
      float rg = 1.f/(1.f + __expf(-(ir+hr)));
      float zg = 1.f/(1.f + __expf(-(iz+hz)));
      float nv = in_ + rg*hn;
      float av = fminf(fabsf(nv), 15.f);
      float e2 = __expf(2.f*av);
      float tg = 1.f - 2.f/(e2 + 1.f);
      tg = (nv < 0.f)? -tg : tg;
      float hp = xf[(size_t)node*CC + c];
      float h = (1.f - zg)*tg + zg*hp;
      if(valid) out_f[(size_t)node*CC + c] = h;
    }
  }
}

extern "C" void kernel_launch(void* const* d_in, const int* in_sizes, int n_in,
                              void* d_out, int out_size, void* d_ws, size_t ws_size,
                              hipStream_t stream){
  const float* x0     = (const float*)d_in[0];
  const int*   ei     = (const int*)d_in[1];
  const float* weight = (const float*)d_in[2];
  const float* w_ih   = (const float*)d_in[3];
  const float* w_hh   = (const float*)d_in[4];
  const float* b_ih   = (const float*)d_in[5];
  const float* b_hh   = (const float*)d_in[6];
  float* out = (float*)d_out;

  const int* srcv = ei;        // edge_index[0]
  const int* dstv = ei + NE;   // edge_index[1]

  char* ws = (char*)d_ws;
  size_t off = 0;
  auto carve = [&](size_t bytes)->char*{
    char* p = ws + off;
    off += (bytes + 255) & ~(size_t)255;
    return p;
  };
  int* counts   = (int*)carve((size_t)NN*4);
  int* offsets  = (int*)carve((size_t)NN*4);
  int* cursor   = (int*)carve((size_t)NN*4);
  int* gcur     = (int*)carve(4);
  int* ssrc     = (int*)carve((size_t)NE*4);
  float* xfA    = (float*)carve((size_t)NN*CC*4);
  float* xfB    = (float*)carve((size_t)NN*CC*4);
  uint16_t* gw  = (uint16_t*)carve((size_t)NL*ELEMS_PER_LAYER*2);

  // CSR build (once — edge structure shared by all 3 layers)
  k_zero<<<(NN+255)/256, 256, 0, stream>>>(counts, gcur);
  k_hist<<<(NE+255)/256, 256, 0, stream>>>(dstv, counts);
  k_assign<<<(NN+255)/256, 256, 0, stream>>>(counts, offsets, cursor, gcur);
  k_fill<<<(NE+255)/256, 256, 0, stream>>>(srcv, dstv, cursor, ssrc);

  // Fold Wc = W @ w_ih^T, pack all weights fragment-linear (hi/lo for Wc, hi for Whh)
  k_pack_w<<<((NL*288*CC + 288*CC)+255)/256, 256, 0, stream>>>(weight, w_ih, w_hh, gw);

  // ping-pong buffers: fused kernel gathers random rows while writing, so
  // in-place is a cross-block race — always write the other buffer.
  const float* xf_cur = x0;
  for(int l=0; l<NL; l++){
    float* out_f = (l==NL-1) ? out : ((l==0) ? xfA : xfB);
    k_gru_fused<<<(NN/16 + 3)/4, 256, 0, stream>>>(xf_cur, offsets, counts, ssrc,
                                                   gw + (size_t)l*ELEMS_PER_LAYER,
                                                   b_ih, b_hh, out_f);
    xf_cur = out_f;
  }
}